// Round 1
// 5986.428 us; speedup vs baseline: 1.2740x; 1.2740x over previous
//
#include <hip/hip_runtime.h>
#include <cstdint>
#include <cstddef>

#define B_    64
#define NP1   1025
#define N_    1024
#define D_    256
#define DP1   257
#define L_    4
#define H_    4
#define MT    1024   // ZbT row length (m dim); m=1024 (masked key) simply excluded
#define NCHE  32     // 32 chunks x 32 m = 1024 (mask folded into loop bound)
#define IPAD  272
#define TROWS 1025   // T rows per (b,h): n=0..1024

typedef __bf16 bf16;
typedef bf16 bf16x4 __attribute__((ext_vector_type(4)));
typedef bf16 bf16x8 __attribute__((ext_vector_type(8)));
typedef float f32x4 __attribute__((ext_vector_type(4)));

__device__ __forceinline__ f32x4 mfma16(bf16x8 a, bf16x8 b, f32x4 c) {
    return __builtin_amdgcn_mfma_f32_16x16x32_bf16(a, b, c, 0, 0, 0);
}

__device__ __forceinline__ void async16(const void* g, void* l) {
    __builtin_amdgcn_global_load_lds(
        (const __attribute__((address_space(1))) void*)g,
        (__attribute__((address_space(3))) void*)l, 16, 0, 0);
}

// ---------------------------------------------------------------------------
__global__ void k_prep_pq(const float* __restrict__ ap,
                          bf16* __restrict__ Pb, bf16* __restrict__ Qt) {
    int idx = blockIdx.x * 256 + threadIdx.x;   // L*H*D*D = 1048576
    int j  = idx & 255;
    int i  = (idx >> 8) & 255;
    int lh = idx >> 16;
    const float* base = ap + (size_t)lh * 2 * D_ * D_;
    float p = base[i * D_ + j];
    float q = base[D_ * D_ + i * D_ + j];
    Pb[((size_t)lh * D_ + i) * D_ + j] = (bf16)p;
    Qt[((size_t)lh * D_ + j) * D_ + i] = (bf16)q;   // Qt[j][i] = Q[i][j]
}

// ---------------------------------------------------------------------------
__global__ void k_z2b(const float* __restrict__ Z, bf16* __restrict__ Zb) {
    int n = blockIdx.x, b = blockIdx.y, i = threadIdx.x;
    Zb[((size_t)b * N_ + n) * D_ + i] = (bf16)Z[((size_t)b * NP1 + n) * DP1 + i];
}

// ---------------------------------------------------------------------------
// ZbT[b][j][m] = Z[b][m][j] for j<257, m<1024 (mask = dropping m=1024).
// Tiled LDS transpose, coalesced both sides.
// ---------------------------------------------------------------------------
__global__ __launch_bounds__(256) void k_zbt(const float* __restrict__ Z,
                                             bf16* __restrict__ ZbT) {
    __shared__ float t[64][65];
    int m0 = blockIdx.x * 64, j0 = blockIdx.y * 64, b = blockIdx.z;
    int c = threadIdx.x & 63, r0 = threadIdx.x >> 6;
#pragma unroll
    for (int s = 0; s < 16; s++) {
        int r = s * 4 + r0;
        int j = j0 + c;
        t[r][c] = (j < DP1) ? Z[((size_t)b * NP1 + m0 + r) * DP1 + j] : 0.f;
    }
    __syncthreads();
#pragma unroll
    for (int s = 0; s < 16; s++) {
        int rr = s * 4 + r0;
        int j = j0 + rr;
        if (j < DP1)
            ZbT[((size_t)b * DP1 + j) * MT + m0 + c] = (bf16)t[c][rr];
    }
}

// ---------------------------------------------------------------------------
// Fused attention, T-form: per head, T[n,j] = sum_{m<1024} relu(ZQ.Z^T)[n,m]*Z[m,j].
// Same verified inner structure as before (ZQ phase, S-phase, sl roundtrips,
// dbuf async staging, XOR swizzles); KT replaced by h-invariant ZbT so the
// per-XCD staging working set (~4 b x 1.0 MB) fits the 4 MB L2.
// Grid: 512 main blocks (8 n-blocks x 64 b, bijective XCD swizzle, exactly
// 2 dispatch rounds at 1 block/CU) + 64 light blocks for query row n=1024.
// ---------------------------------------------------------------------------
__global__ __launch_bounds__(256, 1) void k_attn(const bf16* __restrict__ Zb,
                                                 const bf16* __restrict__ ZbT,
                                                 const bf16* __restrict__ Qt,
                                                 const float* __restrict__ Z,
                                                 bf16* __restrict__ T,
                                                 bf16* __restrict__ Tlab,
                                                 int layer) {
    __shared__ bf16 zbS[2][32][256];   // XOR-swizzled: f(r) = r&7
    __shared__ bf16 ztS[2][IPAD][32];  // f(r) = (r>>1)&3 ; rows 257..271 unused garbage (write-guarded)
    __shared__ bf16 sl[4][32][40];     // per-wave roundtrip scratch

    const int tid  = threadIdx.x;
    const int id   = blockIdx.x;
    const int wave = tid >> 6, lane = tid & 63;
    const int quad = lane >> 4, l16 = lane & 15;

    if (id >= 512) {
        // ---- query row n = 1024 (one light block per b) ----
        const int b = id - 512;
        float* z1  = (float*)&zbS[0][0][0];  // 256 f32
        float* zqS = z1 + 256;               // 256 f32
        float* sS  = zqS + 256;              // 1024 f32
        z1[tid] = Z[((size_t)b * NP1 + N_) * DP1 + tid];
        __syncthreads();
        for (int h = 0; h < H_; h++) {
            const bf16* Qth = Qt + (size_t)(layer * H_ + h) * D_ * D_;
            {
                float a = 0.f;
                const bf16* qr = Qth + (size_t)tid * D_;   // Qt[j=tid][i]
                for (int i8 = 0; i8 < 32; i8++) {
                    bf16x8 q = *(const bf16x8*)(qr + i8 * 8);
#pragma unroll
                    for (int k = 0; k < 8; k++) a += z1[i8 * 8 + k] * (float)q[k];
                }
                zqS[tid] = a;
            }
            __syncthreads();
            for (int m = tid; m < N_; m += 256) {
                float a = 0.f;
                const bf16* zr = Zb + ((size_t)b * N_ + m) * D_;
                for (int j8 = 0; j8 < 32; j8++) {
                    bf16x8 z8 = *(const bf16x8*)(zr + j8 * 8);
#pragma unroll
                    for (int k = 0; k < 8; k++) a += zqS[j8 * 8 + k] * (float)z8[k];
                }
                sS[m] = a > 0.f ? a : 0.f;
            }
            __syncthreads();
            bf16* Th = T + (size_t)(b * H_ + h) * TROWS * D_;
            for (int j = tid; j < DP1; j += 256) {
                float a = 0.f;
                const bf16* tr = ZbT + ((size_t)b * DP1 + j) * MT;
                for (int m8 = 0; m8 < 128; m8++) {
                    bf16x8 t8 = *(const bf16x8*)(tr + m8 * 8);
#pragma unroll
                    for (int k = 0; k < 8; k++) a += sS[m8 * 8 + k] * (float)t8[k];
                }
                if (j < D_) Th[(size_t)N_ * D_ + j] = (bf16)a;
                else        Tlab[(size_t)(b * H_ + h) * TROWS + N_] = (bf16)a;
            }
            __syncthreads();
        }
        return;
    }

    // bijective mapping: round 0 (ids 0..255) covers b 0..31, all 8 n-blocks of
    // a given b on one XCD (id&7) so its Zb+ZbT (~1.0 MB) is L2-shared.
    const int xcd = id & 7, u = id >> 3;
    const int b   = xcd + 8 * (u & 3) + 32 * (u >> 5);
    const int bx  = (u >> 2) & 7;
    const int n0w = bx * 128 + wave * 32;

    const bf16* Zbb  = Zb  + (size_t)b * N_ * D_;
    const bf16* ZbTb = ZbT + (size_t)b * DP1 * MT;

    const int zrow  = wave * 2 + (lane >> 5);
    const int zscol = ((lane & 31) ^ (zrow & 7)) * 8;
    const int krow  = wave * 16 + (lane >> 2);
    const int kscol = ((lane & 3) ^ ((lane >> 3) & 3)) * 8;
    const int xs    = l16 & 7;
    const int kf    = (l16 >> 1) & 3;

    auto stage = [&](int mc_, int p_) {
        int m0 = mc_ * 32;
        const bf16* zsrc = Zbb + (size_t)(m0 + zrow) * D_ + zscol;
#pragma unroll
        for (int t = 0; t < 4; t++)
            async16(zsrc + (size_t)t * 8 * D_, &zbS[p_][t * 8 + wave * 2][0]);
        const bf16* ksrc = ZbTb + (size_t)krow * MT + m0 + kscol;
#pragma unroll
        for (int t = 0; t < 4; t++)
            async16(ksrc + (size_t)t * 64 * MT, &ztS[p_][t * 64 + wave * 16][0]);
        if (wave == 0)
            async16(ksrc + (size_t)256 * MT, &ztS[p_][256][0]);
    };

    for (int h = 0; h < H_; h++) {
        const bf16* Qth = Qt + (size_t)(layer * H_ + h) * D_ * D_;

        if (h == 0) stage(0, 0);   // overlap first-chunk fill with ZQ phase

        f32x4 acc[2][17];
#pragma unroll
        for (int ns = 0; ns < 2; ns++)
#pragma unroll
            for (int it = 0; it < 17; it++) acc[ns][it] = (f32x4){0.f, 0.f, 0.f, 0.f};

        // ---- phase 1: ZQ^T -> zqa frags (b64-packed roundtrip) ----
        bf16x8 zqa[2][8];
#pragma unroll 2
        for (int jc = 0; jc < 8; jc++) {
            f32x4 c00 = (f32x4){0.f,0.f,0.f,0.f}, c01 = c00, c10 = c00, c11 = c00;
#pragma unroll
            for (int kc = 0; kc < 8; kc++) {
                const bf16* qb = Qth + (size_t)(jc * 32 + l16) * D_ + kc * 32 + quad * 8;
                const bf16* az = Zbb + (size_t)(n0w + l16) * D_ + kc * 32 + quad * 8;
                bf16x8 q0 = *(const bf16x8*)(qb);
                bf16x8 q1 = *(const bf16x8*)(qb + 16 * D_);
                bf16x8 a0 = *(const bf16x8*)(az);
                bf16x8 a1 = *(const bf16x8*)(az + 16 * D_);
                c00 = mfma16(q0, a0, c00);
                c01 = mfma16(q0, a1, c01);
                c10 = mfma16(q1, a0, c10);
                c11 = mfma16(q1, a1, c11);
            }
            f32x4 cv[2][2] = {{c00, c01}, {c10, c11}};
#pragma unroll
            for (int jt = 0; jt < 2; jt++)
#pragma unroll
                for (int ns = 0; ns < 2; ns++) {
                    bf16x4 pk;
#pragma unroll
                    for (int r = 0; r < 4; r++) pk[r] = (bf16)cv[jt][ns][r];
                    *(bf16x4*)(&sl[wave][ns * 16 + l16][jt * 16 + quad * 4]) = pk;
                }
#pragma unroll
            for (int ns = 0; ns < 2; ns++)
                zqa[ns][jc] = *(const bf16x8*)(&sl[wave][ns * 16 + l16][quad * 8]);
        }

        if (h == 0) __syncthreads();
        // h>0: chunk 0 staged during previous head's last iteration (ZbT h-invariant)

        for (int mc = 0; mc < NCHE; mc++) {
            int p = mc & 1;
            if (mc + 1 < NCHE)
                stage(mc + 1, p ^ 1);
            else if (h + 1 < H_)
                stage(0, p ^ 1);   // same data, next head's chunk 0

            // ---- S^T = relu(Zb_chunk . ZQ^T), b64-packed roundtrip ----
#pragma unroll
            for (int mt = 0; mt < 2; mt++) {
                f32x4 st0 = (f32x4){0.f,0.f,0.f,0.f}, st1 = st0;
                const bf16* zr = &zbS[p][mt * 16 + l16][0];
#pragma unroll
                for (int kc = 0; kc < 8; kc++) {
                    bf16x8 az = *(const bf16x8*)(zr + (((kc * 4 + quad) ^ xs) * 8));
                    st0 = mfma16(az, zqa[0][kc], st0);
                    st1 = mfma16(az, zqa[1][kc], st1);
                }
                bf16x4 p0, p1;
#pragma unroll
                for (int r = 0; r < 4; r++) {
                    p0[r] = (bf16)(st0[r] > 0.f ? st0[r] : 0.f);
                    p1[r] = (bf16)(st1[r] > 0.f ? st1[r] : 0.f);
                }
                *(bf16x4*)(&sl[wave][l16][mt * 16 + quad * 4])      = p0;
                *(bf16x4*)(&sl[wave][16 + l16][mt * 16 + quad * 4]) = p1;
            }
            bf16x8 sfrag[2];
#pragma unroll
            for (int ns = 0; ns < 2; ns++)
                sfrag[ns] = *(const bf16x8*)(&sl[wave][ns * 16 + l16][quad * 8]);

            // ---- acc(T) += S . ZbT_chunk^T ----
#pragma unroll
            for (int it = 0; it < 17; it++) {
                const bf16* kr = &ztS[p][it * 16 + l16][0];
                bf16x8 bk = *(const bf16x8*)(kr + ((quad ^ kf) * 8));
                acc[0][it] = mfma16(sfrag[0], bk, acc[0][it]);
                acc[1][it] = mfma16(sfrag[1], bk, acc[1][it]);
            }
            __syncthreads();
        }

        // ---- per-head epilogue: write T (bf16); j=256 goes to Tlab ----
        bf16* Th  = T    + (size_t)(b * H_ + h) * TROWS * D_;
        bf16* Tlh = Tlab + (size_t)(b * H_ + h) * TROWS;
#pragma unroll
        for (int ns = 0; ns < 2; ns++)
#pragma unroll
            for (int it = 0; it < 17; it++)
#pragma unroll
                for (int r = 0; r < 4; r++) {
                    int n = n0w + ns * 16 + quad * 4 + r;   // always < 1024
                    float v = acc[ns][it][r];
                    if (it < 16)
                        Th[(size_t)n * D_ + it * 16 + l16] = (bf16)v;
                    else if (l16 == 0)
                        Tlh[n] = (bf16)v;
                }
    }
}

// ---------------------------------------------------------------------------
// Z[b,n,i] += (1/N) * sum_h T_h[n,:] . P_h[i,:]   (i<256), plus label column
// i=256 pass-through from Tlab. P is 128 KB/head, shared by all blocks -> L2.
// ---------------------------------------------------------------------------
__global__ __launch_bounds__(256, 2) void k_post(const bf16* __restrict__ T,
                                                 const bf16* __restrict__ Tlab,
                                                 const bf16* __restrict__ Pb,
                                                 float* __restrict__ Z, int layer) {
    const int tid  = threadIdx.x;
    const int wave = tid >> 6, lane = tid & 63;
    const int quad = lane >> 4, l16 = lane & 15;
    const int id = blockIdx.x;
    int b, bx;
    if (id < 512) {
        int xcd = id & 7, u = id >> 3;
        b  = xcd + 8 * (u & 3) + 32 * (u >> 5);
        bx = (u >> 2) & 7;
    } else { b = id - 512; bx = 8; }
    const int n0w = bx * 128 + wave * 32;

    f32x4 acc[2][16];
#pragma unroll
    for (int ns = 0; ns < 2; ns++)
#pragma unroll
        for (int it = 0; it < 16; it++) acc[ns][it] = (f32x4){0.f, 0.f, 0.f, 0.f};

    for (int h = 0; h < H_; h++) {
        const bf16* Th = T  + (size_t)(b * H_ + h) * TROWS * D_;
        const bf16* Ph = Pb + (size_t)(layer * H_ + h) * D_ * D_;
#pragma unroll 2
        for (int kc = 0; kc < 8; kc++) {
            bf16x8 af[2];
#pragma unroll
            for (int ns = 0; ns < 2; ns++) {
                int row = n0w + ns * 16 + l16;
                bf16x8 v = {};
                if (row <= N_)
                    v = *(const bf16x8*)(Th + (size_t)row * D_ + kc * 32 + quad * 8);
                af[ns] = v;
            }
#pragma unroll
            for (int it = 0; it < 16; it++) {
                bf16x8 bp = *(const bf16x8*)(Ph + (size_t)(it * 16 + l16) * D_ + kc * 32 + quad * 8);
                acc[0][it] = mfma16(af[0], bp, acc[0][it]);
                acc[1][it] = mfma16(af[1], bp, acc[1][it]);
            }
        }
    }

    const float inv = 1.0f / (float)N_;
#pragma unroll
    for (int ns = 0; ns < 2; ns++)
#pragma unroll
        for (int it = 0; it < 16; it++)
#pragma unroll
            for (int r = 0; r < 4; r++) {
                int n = n0w + ns * 16 + quad * 4 + r;
                int i = it * 16 + l16;                     // < 256
                if (n < NP1)
                    Z[((size_t)b * NP1 + n) * DP1 + i] += acc[ns][it][r] * inv;
            }
    // label column i = 256
    if (tid < 128) {
        int n = bx * 128 + tid;
        if (n < NP1) {
            float s = 0.f;
#pragma unroll
            for (int h = 0; h < H_; h++)
                s += (float)Tlab[(size_t)(b * H_ + h) * TROWS + n];
            Z[((size_t)b * NP1 + n) * DP1 + D_] += s * inv;
        }
    }
}

// ---------------------------------------------------------------------------
extern "C" void kernel_launch(void* const* d_in, const int* in_sizes, int n_in,
                              void* d_out, int out_size, void* d_ws, size_t ws_size,
                              hipStream_t stream) {
    const float* Zin = (const float*)d_in[0];
    const float* ap  = (const float*)d_in[1];
    float* Z = (float*)d_out;

    char* ws = (char*)d_ws;
    const size_t sz_Zb  = (size_t)B_ * N_ * D_ * sizeof(bf16);           // 33.6 MB
    const size_t sz_ZbT = (size_t)B_ * DP1 * MT * sizeof(bf16);          // 33.7 MB
    const size_t sz_T   = (size_t)B_ * H_ * TROWS * D_ * sizeof(bf16);   // 134.5 MB
    const size_t sz_Tl  = (size_t)B_ * H_ * TROWS * sizeof(bf16);        // 0.5 MB
    const size_t sz_P   = (size_t)L_ * H_ * D_ * D_ * sizeof(bf16);      // 2 MB
    bf16* Zb  = (bf16*)ws;
    bf16* ZbT = (bf16*)(ws + sz_Zb);
    bf16* Tb  = (bf16*)(ws + sz_Zb + sz_ZbT);
    bf16* Tl  = (bf16*)(ws + sz_Zb + sz_ZbT + sz_T);
    bf16* Pb  = (bf16*)(ws + sz_Zb + sz_ZbT + sz_T + sz_Tl);
    bf16* Qt  = (bf16*)(ws + sz_Zb + sz_ZbT + sz_T + sz_Tl + sz_P);

    hipMemcpyAsync(Z, Zin, (size_t)B_ * NP1 * DP1 * sizeof(float),
                   hipMemcpyDeviceToDevice, stream);

    k_prep_pq<<<dim3((L_ * H_ * D_ * D_) / 256), 256, 0, stream>>>(ap, Pb, Qt);

    for (int l = 0; l < L_; l++) {
        k_z2b<<<dim3(N_, B_), 256, 0, stream>>>(Z, Zb);
        k_zbt<<<dim3(N_ / 64, 5, B_), 256, 0, stream>>>(Z, ZbT);
        k_attn<<<dim3(576), 256, 0, stream>>>(Zb, ZbT, Qt, Z, Tb, Tl, l);
        k_post<<<dim3(576), 256, 0, stream>>>(Tb, Tl, Pb, Z, l);
    }
}

// Round 3
// 4932.576 us; speedup vs baseline: 1.5462x; 1.2137x over previous
//
#include <hip/hip_runtime.h>
#include <cstdint>
#include <cstddef>

#define B_    64
#define NP1   1025
#define N_    1024
#define D_    256
#define DP1   257
#define L_    4
#define H_    4
#define MT    1024   // ZbT row length (m dim); m=1024 (masked key) excluded
#define NCHE  32     // 32 chunks x 32 m = 1024
#define IPAD  272
#define TR_   1024   // T rows per (b,h): n=0..1023 (row 1024 handled in k_post)

typedef __bf16 bf16;
typedef bf16 bf16x4 __attribute__((ext_vector_type(4)));
typedef bf16 bf16x8 __attribute__((ext_vector_type(8)));
typedef float f32x4 __attribute__((ext_vector_type(4)));

__device__ __forceinline__ f32x4 mfma16(bf16x8 a, bf16x8 b, f32x4 c) {
    return __builtin_amdgcn_mfma_f32_16x16x32_bf16(a, b, c, 0, 0, 0);
}

__device__ __forceinline__ void async16(const void* g, void* l) {
    __builtin_amdgcn_global_load_lds(
        (const __attribute__((address_space(1))) void*)g,
        (__attribute__((address_space(3))) void*)l, 16, 0, 0);
}

// ---------------------------------------------------------------------------
__global__ void k_prep_pq(const float* __restrict__ ap,
                          bf16* __restrict__ Pb, bf16* __restrict__ Qt) {
    int idx = blockIdx.x * 256 + threadIdx.x;   // L*H*D*D = 1048576
    int j  = idx & 255;
    int i  = (idx >> 8) & 255;
    int lh = idx >> 16;
    const float* base = ap + (size_t)lh * 2 * D_ * D_;
    float p = base[i * D_ + j];
    float q = base[D_ * D_ + i * D_ + j];
    Pb[((size_t)lh * D_ + i) * D_ + j] = (bf16)p;
    Qt[((size_t)lh * D_ + j) * D_ + i] = (bf16)q;   // Qt[j][i] = Q[i][j]
}

// ---------------------------------------------------------------------------
// Fused: Zb[b][m][j] = Z[b][m][j] (j<256) and ZbT[b][j][m] = Z[b][m][j]
// (j<257), m<1024. Z read once.
// ---------------------------------------------------------------------------
__global__ __launch_bounds__(256) void k_zbt(const float* __restrict__ Z,
                                             bf16* __restrict__ Zb,
                                             bf16* __restrict__ ZbT) {
    __shared__ float t[64][65];
    int m0 = blockIdx.x * 64, j0 = blockIdx.y * 64, b = blockIdx.z;
    int c = threadIdx.x & 63, r0 = threadIdx.x >> 6;
#pragma unroll
    for (int s = 0; s < 16; s++) {
        int r = s * 4 + r0;
        int j = j0 + c;
        float v = (j < DP1) ? Z[((size_t)b * NP1 + m0 + r) * DP1 + j] : 0.f;
        t[r][c] = v;
        if (j < D_) Zb[((size_t)b * N_ + m0 + r) * D_ + j] = (bf16)v;
    }
    __syncthreads();
#pragma unroll
    for (int s = 0; s < 16; s++) {
        int rr = s * 4 + r0;
        int j = j0 + rr;
        if (j < DP1)
            ZbT[((size_t)b * DP1 + j) * MT + m0 + c] = (bf16)t[c][rr];
    }
}

// ---------------------------------------------------------------------------
// Fused attention, T-form, 8-wave blocks: per head,
// T[n,j] = sum_{m<1024} relu(ZQ.Z^T)[n,m]*Z[m,j].
// One 512-thread block covers 256 n-rows; 8 waves share the staged chunk
// (2 waves/SIMD resident -> latency hiding).
// Grid: 256 blocks = 4 n-blocks x 64 b = exactly one dispatch round,
// XCD-swizzled so a b's 4 sibling blocks share one XCD's L2.
// ---------------------------------------------------------------------------
__global__ __launch_bounds__(512, 1) void k_attn(const bf16* __restrict__ Zb,
                                                 const bf16* __restrict__ ZbT,
                                                 const bf16* __restrict__ Qt,
                                                 bf16* __restrict__ T,
                                                 bf16* __restrict__ Tlab,
                                                 int layer) {
    __shared__ bf16 zbS[2][32][256];   // XOR-swizzled: f(r) = r&7
    __shared__ bf16 ztS[2][IPAD][32];  // f(r) = (r>>1)&3 ; rows 257..271 garbage (discarded cols)
    __shared__ bf16 sl[8][32][40];     // per-wave roundtrip scratch

    const int tid  = threadIdx.x;
    const int id   = blockIdx.x;
    const int wave = tid >> 6, lane = tid & 63;
    const int quad = lane >> 4, l16 = lane & 15;

    // bijective XCD mapping: 32 blocks per XCD = 8 b x 4 n-blocks
    const int xcd = id & 7, u = id >> 3;
    const int b   = xcd + 8 * (u & 7);
    const int bx  = u >> 3;             // 0..3
    const int n0w = bx * 256 + wave * 32;

    const bf16* Zbb  = Zb  + (size_t)b * N_ * D_;
    const bf16* ZbTb = ZbT + (size_t)b * DP1 * MT;

    const int zrow  = wave * 2 + (lane >> 5);          // 0..15
    const int zscol = ((lane & 31) ^ (zrow & 7)) * 8;
    const int krow  = wave * 16 + (lane >> 2);         // 0..127
    const int kscol = ((lane & 3) ^ ((lane >> 3) & 3)) * 8;
    const int xs    = l16 & 7;
    const int kf    = (l16 >> 1) & 3;

    auto stage = [&](int mc_, int p_) {
        int m0 = mc_ * 32;
        const bf16* zsrc = Zbb + (size_t)(m0 + zrow) * D_ + zscol;
#pragma unroll
        for (int t = 0; t < 2; t++)
            async16(zsrc + (size_t)t * 16 * D_, &zbS[p_][t * 16 + wave * 2][0]);
        const bf16* ksrc = ZbTb + (size_t)krow * MT + m0 + kscol;
#pragma unroll
        for (int t = 0; t < 2; t++)
            async16(ksrc + (size_t)t * 128 * MT, &ztS[p_][t * 128 + wave * 16][0]);
        if (wave == 0)
            async16(ksrc + (size_t)256 * MT, &ztS[p_][256][0]);
    };

    for (int h = 0; h < H_; h++) {
        const bf16* Qth = Qt + (size_t)(layer * H_ + h) * D_ * D_;

        if (h == 0) stage(0, 0);   // overlap first-chunk fill with ZQ phase

        f32x4 acc[2][17];
#pragma unroll
        for (int ns = 0; ns < 2; ns++)
#pragma unroll
            for (int it = 0; it < 17; it++) acc[ns][it] = (f32x4){0.f, 0.f, 0.f, 0.f};

        // ---- phase 1: ZQ^T -> zqa frags (b64-packed roundtrip) ----
        bf16x8 zqa[2][8];
#pragma unroll 2
        for (int jc = 0; jc < 8; jc++) {
            f32x4 c00 = (f32x4){0.f,0.f,0.f,0.f}, c01 = c00, c10 = c00, c11 = c00;
#pragma unroll
            for (int kc = 0; kc < 8; kc++) {
                const bf16* qb = Qth + (size_t)(jc * 32 + l16) * D_ + kc * 32 + quad * 8;
                const bf16* az = Zbb + (size_t)(n0w + l16) * D_ + kc * 32 + quad * 8;
                bf16x8 q0 = *(const bf16x8*)(qb);
                bf16x8 q1 = *(const bf16x8*)(qb + 16 * D_);
                bf16x8 a0 = *(const bf16x8*)(az);
                bf16x8 a1 = *(const bf16x8*)(az + 16 * D_);
                c00 = mfma16(q0, a0, c00);
                c01 = mfma16(q0, a1, c01);
                c10 = mfma16(q1, a0, c10);
                c11 = mfma16(q1, a1, c11);
            }
            f32x4 cv[2][2] = {{c00, c01}, {c10, c11}};
#pragma unroll
            for (int jt = 0; jt < 2; jt++)
#pragma unroll
                for (int ns = 0; ns < 2; ns++) {
                    bf16x4 pk;
#pragma unroll
                    for (int r = 0; r < 4; r++) pk[r] = (bf16)cv[jt][ns][r];
                    *(bf16x4*)(&sl[wave][ns * 16 + l16][jt * 16 + quad * 4]) = pk;
                }
#pragma unroll
            for (int ns = 0; ns < 2; ns++)
                zqa[ns][jc] = *(const bf16x8*)(&sl[wave][ns * 16 + l16][quad * 8]);
        }

        if (h == 0) __syncthreads();
        // h>0: chunk 0 staged during previous head's last iteration (ZbT h-invariant)

        for (int mc = 0; mc < NCHE; mc++) {
            int p = mc & 1;
            if (mc + 1 < NCHE)
                stage(mc + 1, p ^ 1);
            else if (h + 1 < H_)
                stage(0, p ^ 1);   // same data, next head's chunk 0

            // ---- S^T = relu(Zb_chunk . ZQ^T), b64-packed roundtrip ----
#pragma unroll
            for (int mt = 0; mt < 2; mt++) {
                f32x4 st0 = (f32x4){0.f,0.f,0.f,0.f}, st1 = st0;
                const bf16* zr = &zbS[p][mt * 16 + l16][0];
#pragma unroll
                for (int kc = 0; kc < 8; kc++) {
                    bf16x8 az = *(const bf16x8*)(zr + (((kc * 4 + quad) ^ xs) * 8));
                    st0 = mfma16(az, zqa[0][kc], st0);
                    st1 = mfma16(az, zqa[1][kc], st1);
                }
                bf16x4 p0, p1;
#pragma unroll
                for (int r = 0; r < 4; r++) {
                    p0[r] = (bf16)(st0[r] > 0.f ? st0[r] : 0.f);
                    p1[r] = (bf16)(st1[r] > 0.f ? st1[r] : 0.f);
                }
                *(bf16x4*)(&sl[wave][l16][mt * 16 + quad * 4])      = p0;
                *(bf16x4*)(&sl[wave][16 + l16][mt * 16 + quad * 4]) = p1;
            }
            bf16x8 sfrag[2];
#pragma unroll
            for (int ns = 0; ns < 2; ns++)
                sfrag[ns] = *(const bf16x8*)(&sl[wave][ns * 16 + l16][quad * 8]);

            // ---- acc(T) += S . ZbT_chunk^T ----
#pragma unroll
            for (int it = 0; it < 17; it++) {
                const bf16* kr = &ztS[p][it * 16 + l16][0];
                bf16x8 bk = *(const bf16x8*)(kr + ((quad ^ kf) * 8));
                acc[0][it] = mfma16(sfrag[0], bk, acc[0][it]);
                acc[1][it] = mfma16(sfrag[1], bk, acc[1][it]);
            }
            __syncthreads();
        }

        // ---- per-head epilogue: write T (bf16); j=256 goes to Tlab ----
        bf16* Th  = T    + (size_t)(b * H_ + h) * TR_ * D_;
        bf16* Tlh = Tlab + (size_t)(b * H_ + h) * TR_;
#pragma unroll
        for (int ns = 0; ns < 2; ns++)
#pragma unroll
            for (int it = 0; it < 17; it++)
#pragma unroll
                for (int r = 0; r < 4; r++) {
                    int n = n0w + ns * 16 + quad * 4 + r;   // < 1024
                    float v = acc[ns][it][r];
                    if (it < 16)
                        Th[(size_t)n * D_ + it * 16 + l16] = (bf16)v;
                    else if (l16 == 0)
                        Tlh[n] = (bf16)v;
                }
    }
}

// ---------------------------------------------------------------------------
// Z[b,n,i] += (1/N) * sum_h T_h[n,:] . P_h[i,:]   (i<256), plus label column
// i=256 from Tlab. Blocks 512..575: scalar path for query row n=1024,
// INCLUDING the P contraction (res = T_row . P^T, label passes through).
// ---------------------------------------------------------------------------
__global__ __launch_bounds__(256, 2) void k_post(const bf16* __restrict__ T,
                                                 const bf16* __restrict__ Tlab,
                                                 const bf16* __restrict__ Pb,
                                                 const bf16* __restrict__ Zb,
                                                 const bf16* __restrict__ ZbT,
                                                 const bf16* __restrict__ Qt,
                                                 float* __restrict__ Z, int layer) {
    __shared__ float lz1[256];
    __shared__ float lzq[256];
    __shared__ float lsS[1024];
    __shared__ float lT[256];
    __shared__ float llab[256];

    const int tid  = threadIdx.x;
    const int id   = blockIdx.x;

    if (id >= 512) {
        // ---- query row n = 1024 (one block per b), scalar GEMV chain ----
        const int b = id - 512;
        const bf16* Zbb  = Zb  + (size_t)b * N_ * D_;
        const bf16* tr   = ZbT + ((size_t)b * DP1 + tid) * MT;  // row j=tid
        const bf16* zlab = ZbT + ((size_t)b * DP1 + D_) * MT;   // row j=256
        lz1[tid] = Z[((size_t)b * NP1 + N_) * DP1 + tid];
        float outacc = 0.f, labacc = 0.f;
        __syncthreads();
        for (int h = 0; h < H_; h++) {
            const bf16* Qth = Qt + (size_t)(layer * H_ + h) * D_ * D_;
            const bf16* Ph  = Pb + (size_t)(layer * H_ + h) * D_ * D_;
            {   // zq[j] = sum_i z1[i] Q[i][j] ; Qt[j][i] contiguous
                float a = 0.f;
                const bf16* qr = Qth + (size_t)tid * D_;
                for (int i8 = 0; i8 < 32; i8++) {
                    bf16x8 q = *(const bf16x8*)(qr + i8 * 8);
#pragma unroll
                    for (int k = 0; k < 8; k++) a += lz1[i8 * 8 + k] * (float)q[k];
                }
                lzq[tid] = a;
            }
            __syncthreads();
            for (int m = tid; m < N_; m += 256) {
                float a = 0.f;
                const bf16* zr = Zbb + (size_t)m * D_;
                for (int j8 = 0; j8 < 32; j8++) {
                    bf16x8 z8 = *(const bf16x8*)(zr + j8 * 8);
#pragma unroll
                    for (int k = 0; k < 8; k++) a += lzq[j8 * 8 + k] * (float)z8[k];
                }
                lsS[m] = a > 0.f ? a : 0.f;
            }
            __syncthreads();
            {   // T-row: lT[j=tid] = sum_m S[m] * Z[m,j]  (ZbT row contiguous)
                float tv = 0.f;
                for (int m8 = 0; m8 < 128; m8++) {
                    bf16x8 t8 = *(const bf16x8*)(tr + m8 * 8);
#pragma unroll
                    for (int k = 0; k < 8; k++) tv += lsS[m8 * 8 + k] * (float)t8[k];
                }
                lT[tid] = tv;
            }
            for (int m = tid; m < N_; m += 256)
                labacc += lsS[m] * (float)zlab[m];
            __syncthreads();
            {   // P contraction: outacc += sum_j lT[j] * P[i=tid][j]
                const bf16* pr = Ph + (size_t)tid * D_;
                for (int j8 = 0; j8 < 32; j8++) {
                    bf16x8 p8 = *(const bf16x8*)(pr + j8 * 8);
#pragma unroll
                    for (int k = 0; k < 8; k++) outacc += lT[j8 * 8 + k] * (float)p8[k];
                }
            }
            __syncthreads();   // protect lzq/lsS/lT before next head
        }
        const float inv = 1.0f / (float)N_;
        Z[((size_t)b * NP1 + N_) * DP1 + tid] += outacc * inv;
        llab[tid] = labacc;
        __syncthreads();
        if (tid == 0) {
            float s = 0.f;
            for (int t = 0; t < 256; t++) s += llab[t];
            Z[((size_t)b * NP1 + N_) * DP1 + D_] += s * inv;
        }
        return;
    }

    const int wave = tid >> 6, lane = tid & 63;
    const int quad = lane >> 4, l16 = lane & 15;
    const int xcd = id & 7, u = id >> 3;
    const int b   = xcd + 8 * (u & 3) + 32 * (u >> 5);
    const int bx  = (u >> 2) & 7;
    const int n0w = bx * 128 + wave * 32;

    f32x4 acc[2][16];
#pragma unroll
    for (int ns = 0; ns < 2; ns++)
#pragma unroll
        for (int it = 0; it < 16; it++) acc[ns][it] = (f32x4){0.f, 0.f, 0.f, 0.f};

    for (int h = 0; h < H_; h++) {
        const bf16* Th = T  + (size_t)(b * H_ + h) * TR_ * D_;
        const bf16* Ph = Pb + (size_t)(layer * H_ + h) * D_ * D_;
#pragma unroll 2
        for (int kc = 0; kc < 8; kc++) {
            bf16x8 af[2];
#pragma unroll
            for (int ns = 0; ns < 2; ns++) {
                int row = n0w + ns * 16 + l16;   // < 1024
                af[ns] = *(const bf16x8*)(Th + (size_t)row * D_ + kc * 32 + quad * 8);
            }
#pragma unroll
            for (int it = 0; it < 16; it++) {
                bf16x8 bp = *(const bf16x8*)(Ph + (size_t)(it * 16 + l16) * D_ + kc * 32 + quad * 8);
                acc[0][it] = mfma16(af[0], bp, acc[0][it]);
                acc[1][it] = mfma16(af[1], bp, acc[1][it]);
            }
        }
    }

    const float inv = 1.0f / (float)N_;
#pragma unroll
    for (int ns = 0; ns < 2; ns++)
#pragma unroll
        for (int it = 0; it < 16; it++)
#pragma unroll
            for (int r = 0; r < 4; r++) {
                int n = n0w + ns * 16 + quad * 4 + r;   // < 1024
                int i = it * 16 + l16;                   // < 256
                Z[((size_t)b * NP1 + n) * DP1 + i] += acc[ns][it][r] * inv;
            }
    // label column i = 256
    if (tid < 128) {
        int n = bx * 128 + tid;
        float s = 0.f;
#pragma unroll
        for (int h = 0; h < H_; h++)
            s += (float)Tlab[(size_t)(b * H_ + h) * TR_ + n];
        Z[((size_t)b * NP1 + n) * DP1 + D_] += s * inv;
    }
}

// ---------------------------------------------------------------------------
extern "C" void kernel_launch(void* const* d_in, const int* in_sizes, int n_in,
                              void* d_out, int out_size, void* d_ws, size_t ws_size,
                              hipStream_t stream) {
    const float* Zin = (const float*)d_in[0];
    const float* ap  = (const float*)d_in[1];
    float* Z = (float*)d_out;

    char* ws = (char*)d_ws;
    const size_t sz_Zb  = (size_t)B_ * N_ * D_ * sizeof(bf16);          // 33.6 MB
    const size_t sz_ZbT = (size_t)B_ * DP1 * MT * sizeof(bf16);         // 33.7 MB
    const size_t sz_T   = (size_t)B_ * H_ * TR_ * D_ * sizeof(bf16);    // 134.2 MB
    const size_t sz_Tl  = (size_t)B_ * H_ * TR_ * sizeof(bf16);         // 0.5 MB
    const size_t sz_P   = (size_t)L_ * H_ * D_ * D_ * sizeof(bf16);     // 2 MB
    bf16* Zb  = (bf16*)ws;
    bf16* ZbT = (bf16*)(ws + sz_Zb);
    bf16* Tb  = (bf16*)(ws + sz_Zb + sz_ZbT);
    bf16* Tl  = (bf16*)(ws + sz_Zb + sz_ZbT + sz_T);
    bf16* Pb  = (bf16*)(ws + sz_Zb + sz_ZbT + sz_T + sz_Tl);
    bf16* Qt  = (bf16*)(ws + sz_Zb + sz_ZbT + sz_T + sz_Tl + sz_P);

    hipMemcpyAsync(Z, Zin, (size_t)B_ * NP1 * DP1 * sizeof(float),
                   hipMemcpyDeviceToDevice, stream);

    k_prep_pq<<<dim3((L_ * H_ * D_ * D_) / 256), 256, 0, stream>>>(ap, Pb, Qt);

    for (int l = 0; l < L_; l++) {
        k_zbt<<<dim3(N_ / 64, 5, B_), 256, 0, stream>>>(Z, Zb, ZbT);
        k_attn<<<dim3(256), 512, 0, stream>>>(Zb, ZbT, Qt, Tb, Tl, l);
        k_post<<<dim3(576), 256, 0, stream>>>(Tb, Tl, Pb, Zb, ZbT, Qt, Z, l);
    }
}